// Round 5
// baseline (463.007 us; speedup 1.0000x reference)
//
#include <hip/hip_runtime.h>
#include <hip/hip_bf16.h>

// LinearAttention MI355X: B=16, C=256, n=4096, h=8, d=64, SCALE=0.125
// R4: all-K-contiguous bf16 MFMA pipeline, direct-global fragments.
//   K0 cvt_w   : wt = bf16(w_qkv)                       [1536][256]
//   K1 cvt_xT  : xT[b][n][c] = bf16(x[b][c][n])         (LDS 64x64 transpose)
//   K2 qkv_phi : per (b,h,512n): q,k,v GEMMs (B-frags direct from xT,
//                A-frags direct from wt); q-softmax epilogue -> qT bf16;
//                exp(k)/v -> swizzled LDS -> phi MFMA; lsum/phi atomics
//   K3 build_M : Mbf[b,c,h*64+d] = bf16(sum_e w_out[c,h*64+e] phi/lsum)
//   K4 out_mfma: out[b,c,n] = sum_o Mbf[c,o] qT[n,o]  (LDS-free, no barriers)
// ws: qT 64MB | wt 0.75MB | lsum | phi 2MB | Mbf 4MB | xT 32MB = ~103 MiB

typedef __attribute__((ext_vector_type(8))) short bf16x8;
typedef __attribute__((ext_vector_type(4))) float f32x4;

__device__ __forceinline__ unsigned short f2bf(float f) {
    union { float f; unsigned int i; } w; w.f = f;
    unsigned int r = w.i + 0x7FFFu + ((w.i >> 16) & 1u);
    return (unsigned short)(r >> 16);
}

// ---------------- K0: w_qkv fp32 -> bf16 ----------------
__global__ __launch_bounds__(256) void cvt_w(
    const float* __restrict__ wqkv, unsigned short* __restrict__ wt)
{
    int idx = (blockIdx.x * 256 + threadIdx.x) * 8;   // grid 192
    float4 f0 = *(const float4*)&wqkv[idx];
    float4 f1 = *(const float4*)&wqkv[idx + 4];
    unsigned short t[8] = {f2bf(f0.x), f2bf(f0.y), f2bf(f0.z), f2bf(f0.w),
                           f2bf(f1.x), f2bf(f1.y), f2bf(f1.z), f2bf(f1.w)};
    *(uint4*)&wt[idx] = *(uint4*)t;
}

// ---------------- K1: x[b][c][n] f32 -> xT[b][n][c] bf16 ----------------
// grid (64 ntiles, 4 ctiles, 16 b), block 256; 64x64 LDS tile
__global__ __launch_bounds__(256) void cvt_xT(
    const float* __restrict__ x, unsigned short* __restrict__ xT)
{
    const int nb = blockIdx.x * 64, cb = blockIdx.y * 64, b = blockIdx.z;
    __shared__ float Ts[64 * 65];
    const int tid = threadIdx.x;
    const int l = tid & 63, w = tid >> 6;
    const float* xb = x + ((size_t)b * 256 + cb) * 4096 + nb;
#pragma unroll
    for (int p = 0; p < 4; p++) {
        int c = p * 16 + (tid >> 4);
        int n4 = (tid & 15) * 4;
        float4 v = *(const float4*)&xb[(size_t)c * 4096 + n4];
        Ts[c * 65 + n4 + 0] = v.x; Ts[c * 65 + n4 + 1] = v.y;
        Ts[c * 65 + n4 + 2] = v.z; Ts[c * 65 + n4 + 3] = v.w;
    }
    __syncthreads();
    unsigned short t[16];
#pragma unroll
    for (int i = 0; i < 16; i++) t[i] = f2bf(Ts[(w * 16 + i) * 65 + l]);
    unsigned short* dst = xT + ((size_t)b * 4096 + nb + l) * 256 + cb + w * 16;
    *(uint4*)&dst[0] = *(uint4*)&t[0];
    *(uint4*)&dst[8] = *(uint4*)&t[8];
}

// ---------------- K2: fused q/k/v GEMM + softmax(q) + phi ----------------
// grid (8 chunks of 512n, 8 h, 16 b), block 256 (4 waves)
__global__ __launch_bounds__(256) void qkv_phi(
    const unsigned short* __restrict__ xT, const unsigned short* __restrict__ wt,
    unsigned short* __restrict__ qT, float* __restrict__ phi,
    float* __restrict__ lsum)
{
    const int ch = blockIdx.x;
    const int h  = blockIdx.y;
    const int b  = blockIdx.z;
    const int tid  = threadIdx.x;
    const int lane = tid & 63;
    const int w    = tid >> 6;
    const int quad = lane >> 4;
    const int l15  = lane & 15;

    __shared__ unsigned short Es[64 * 128];   // 16 KB expk, XOR-swizzled
    __shared__ unsigned short Vs[64 * 128];   // 16 KB v
    __shared__ unsigned short Qs[128 * 72];   // 18 KB q repack [n][64o]
    __shared__ float red[5 * 128];            // 2.5 KB softmax partials + linv

    const unsigned short* wq  = wt + (size_t)(h * 64) * 256;
    const unsigned short* wk  = wt + (size_t)(512 + h * 64) * 256;
    const unsigned short* wv_ = wt + (size_t)(1024 + h * 64) * 256;

    f32x4 pacc[4];
#pragma unroll
    for (int i = 0; i < 4; i++) pacc[i] = (f32x4)(0.f);
    float lacc[4] = {0.f, 0.f, 0.f, 0.f};

    const int arow = (w * 16 + l15);          // A-fragment row (o within 64)

    for (int st = 0; st < 4; st++) {
        const int nb = ch * 512 + st * 128;
        const unsigned short* xb = xT + ((size_t)b * 4096 + nb) * 256;

        f32x4 accq[8], acck[8], accv[8];
#pragma unroll
        for (int i = 0; i < 8; i++) {
            accq[i] = (f32x4)(0.f); acck[i] = (f32x4)(0.f); accv[i] = (f32x4)(0.f);
        }

        // K-loop: no LDS, no barriers. B-frags from xT, A-frags from wt.
        for (int ks = 0; ks < 8; ks++) {
            const int ko = ks * 32 + quad * 8;
            bf16x8 aq = *(const bf16x8*)&wq [(size_t)arow * 256 + ko];
            bf16x8 ak = *(const bf16x8*)&wk [(size_t)arow * 256 + ko];
            bf16x8 av = *(const bf16x8*)&wv_[(size_t)arow * 256 + ko];
#pragma unroll
            for (int nt = 0; nt < 8; nt++) {
                bf16x8 bf = *(const bf16x8*)&xb[(size_t)(nt * 16 + l15) * 256 + ko];
                accq[nt] = __builtin_amdgcn_mfma_f32_16x16x32_bf16(aq, bf, accq[nt], 0, 0, 0);
                acck[nt] = __builtin_amdgcn_mfma_f32_16x16x32_bf16(ak, bf, acck[nt], 0, 0, 0);
                accv[nt] = __builtin_amdgcn_mfma_f32_16x16x32_bf16(av, bf, accv[nt], 0, 0, 0);
            }
        }

        // ---- q epilogue: softmax over d (64 rows), store qT bf16 ----
#pragma unroll
        for (int nt = 0; nt < 8; nt++) {
#pragma unroll
            for (int r = 0; r < 4; r++) accq[nt][r] = __expf(accq[nt][r]);
            float s = accq[nt][0] + accq[nt][1] + accq[nt][2] + accq[nt][3];
            s += __shfl_xor(s, 16);
            s += __shfl_xor(s, 32);
            if (quad == 0) red[w * 128 + nt * 16 + l15] = s;
        }
        __syncthreads();                       // S2: red written (also fences
                                               // prior subtile's Es/Vs reads)
        if (tid < 128) {
            float t = red[tid] + red[128 + tid] + red[256 + tid] + red[384 + tid];
            red[512 + tid] = 0.125f / t;
        }
        __syncthreads();                       // S3: linv ready
#pragma unroll
        for (int nt = 0; nt < 8; nt++) {
            float li = red[512 + nt * 16 + l15];
            uint2 pp;
            pp.x = (unsigned int)f2bf(accq[nt][0] * li) |
                   ((unsigned int)f2bf(accq[nt][1] * li) << 16);
            pp.y = (unsigned int)f2bf(accq[nt][2] * li) |
                   ((unsigned int)f2bf(accq[nt][3] * li) << 16);
            *(uint2*)&Qs[(nt * 16 + l15) * 72 + w * 16 + quad * 4] = pp;
        }
        __syncthreads();                       // S4: Qs written
        {
            const int n = tid >> 1, half = tid & 1;
            unsigned short* dst = qT + ((size_t)(b * 4096 + nb + n)) * 512 + h * 64 + half * 32;
#pragma unroll
            for (int u = 0; u < 4; u++)
                *(uint4*)&dst[u * 8] = *(uint4*)&Qs[n * 72 + half * 32 + u * 8];
        }

        // ---- k/v epilogue: exp, lsum partials, swizzled deposit ----
#pragma unroll
        for (int r = 0; r < 4; r++) {
            const int dl = quad * 4 + r;                            // d & 15
            const int dbase = (w * 16 + dl) * 256 + (l15 & 7) * 2;  // byte offset
#pragma unroll
            for (int nt = 0; nt < 8; nt++) {
                const int pos = (2 * nt + (l15 >> 3)) ^ dl;
                float ek = __expf(acck[nt][r]);
                lacc[r] += ek;
                *(unsigned short*)((char*)Es + dbase + pos * 16) = f2bf(ek);
                *(unsigned short*)((char*)Vs + dbase + pos * 16) = f2bf(accv[nt][r]);
            }
        }
        __syncthreads();                       // S6: Es/Vs written

        // phi MFMA: phi[d][e] += sum_n expk[d][n] v[e][n], K=128
#pragma unroll
        for (int k2 = 0; k2 < 4; k2++) {
            bf16x8 ae = *(bf16x8*)((char*)Es + (w * 16 + l15) * 256 +
                                   (((k2 * 4 + quad) ^ l15) * 16));
#pragma unroll
            for (int et = 0; et < 4; et++) {
                bf16x8 bv = *(bf16x8*)((char*)Vs + (et * 16 + l15) * 256 +
                                       (((k2 * 4 + quad) ^ l15) * 16));
                pacc[et] = __builtin_amdgcn_mfma_f32_16x16x32_bf16(ae, bv, pacc[et], 0, 0, 0);
            }
        }
        // next subtile's S2 fences these Es/Vs reads before rewrite
    }

    // lsum: reduce over l15 cols then one atomic per d-row
#pragma unroll
    for (int r = 0; r < 4; r++) {
        float s = lacc[r];
        s += __shfl_xor(s, 1); s += __shfl_xor(s, 2);
        s += __shfl_xor(s, 4); s += __shfl_xor(s, 8);
        if (l15 == 0)
            atomicAdd(&lsum[((size_t)b * 8 + h) * 64 + w * 16 + quad * 4 + r], s);
    }
    float* pp = phi + ((size_t)b * 8 + h) * 4096;
#pragma unroll
    for (int et = 0; et < 4; et++)
#pragma unroll
        for (int r = 0; r < 4; r++)
            atomicAdd(&pp[(w * 16 + quad * 4 + r) * 64 + et * 16 + l15], pacc[et][r]);
}

// ---------------- K3: M = w_out · (phi/l), bf16 out ----------------
// grid (8 h, 16 b), block 256 (thread = c)
__global__ __launch_bounds__(256) void build_M(
    const float* __restrict__ phi, const float* __restrict__ lsum,
    const float* __restrict__ w_out, unsigned short* __restrict__ Mbf)
{
    const int h = blockIdx.x, b = blockIdx.y;
    __shared__ float pT[64][68];  // [e][d]
    const float* pp = phi + ((size_t)b * 8 + h) * 4096;  // [d][e]
    const int tid = threadIdx.x;
    const int row = tid >> 2, ls = tid & 3;
#pragma unroll
    for (int u = 0; u < 4; u++) {
        int e0 = (ls + u * 4) * 4;
        float4 v = *(const float4*)&pp[row * 64 + e0];
        pT[e0 + 0][row] = v.x; pT[e0 + 1][row] = v.y;
        pT[e0 + 2][row] = v.z; pT[e0 + 3][row] = v.w;
    }
    __syncthreads();
    const int c = tid;
    float acc[64];
#pragma unroll
    for (int d = 0; d < 64; d++) acc[d] = 0.f;
    for (int e4 = 0; e4 < 16; e4++) {
        float4 wv = *(const float4*)&w_out[(size_t)c * 512 + h * 64 + e4 * 4];
        float wq[4] = {wv.x, wv.y, wv.z, wv.w};
#pragma unroll
        for (int qq = 0; qq < 4; qq++) {
            int e = e4 * 4 + qq;
#pragma unroll
            for (int d4 = 0; d4 < 16; d4++) {
                float4 p = *(const float4*)&pT[e][d4 * 4];
                acc[d4 * 4 + 0] += wq[qq] * p.x;
                acc[d4 * 4 + 1] += wq[qq] * p.y;
                acc[d4 * 4 + 2] += wq[qq] * p.z;
                acc[d4 * 4 + 3] += wq[qq] * p.w;
            }
        }
    }
    const float* lrow = lsum + ((size_t)b * 8 + h) * 64;
    unsigned short tmp[64];
#pragma unroll
    for (int d = 0; d < 64; d++) tmp[d] = f2bf(acc[d] / lrow[d]);
    unsigned short* Mrow = Mbf + ((size_t)b * 256 + c) * 512 + h * 64;
#pragma unroll
    for (int u = 0; u < 8; u++)
        *(uint4*)&Mrow[u * 8] = *(uint4*)&tmp[u * 8];
}

// ---------------- K4: out = Mbf · qT^T, LDS-free ----------------
// grid (32 ntiles, 2 ctiles, 16 b), block 256 (4 waves)
__global__ __launch_bounds__(256) void out_mfma(
    const unsigned short* __restrict__ Mbf, const unsigned short* __restrict__ qT,
    float* __restrict__ out)
{
    const int nb = blockIdx.x * 128;
    const int cb = blockIdx.y * 128;
    const int b  = blockIdx.z;
    const int tid  = threadIdx.x;
    const int lane = tid & 63;
    const int w    = tid >> 6;
    const int quad = lane >> 4;
    const int l15  = lane & 15;

    f32x4 acc[2][8];
#pragma unroll
    for (int t = 0; t < 2; t++)
#pragma unroll
        for (int i = 0; i < 8; i++) acc[t][i] = (f32x4)(0.f);

    const unsigned short* Ab = Mbf + ((size_t)b * 256 + cb) * 512;
    const unsigned short* Bb = qT + ((size_t)b * 4096 + nb) * 512;

    for (int ks = 0; ks < 16; ks++) {
        const int o0 = ks * 32 + quad * 8;
        bf16x8 a0 = *(const bf16x8*)&Ab[(size_t)(w * 32 + l15) * 512 + o0];
        bf16x8 a1 = *(const bf16x8*)&Ab[(size_t)(w * 32 + 16 + l15) * 512 + o0];
#pragma unroll
        for (int nt = 0; nt < 8; nt++) {
            bf16x8 bf = *(const bf16x8*)&Bb[(size_t)(nt * 16 + l15) * 512 + o0];
            acc[0][nt] = __builtin_amdgcn_mfma_f32_16x16x32_bf16(a0, bf, acc[0][nt], 0, 0, 0);
            acc[1][nt] = __builtin_amdgcn_mfma_f32_16x16x32_bf16(a1, bf, acc[1][nt], 0, 0, 0);
        }
    }
    float* ob = out + ((size_t)b * 256 + cb) * 4096 + nb;
#pragma unroll
    for (int t = 0; t < 2; t++)
#pragma unroll
        for (int nt = 0; nt < 8; nt++)
#pragma unroll
            for (int r = 0; r < 4; r++)
                ob[(size_t)(w * 32 + t * 16 + quad * 4 + r) * 4096 + nt * 16 + l15]
                    = acc[t][nt][r];
}

extern "C" void kernel_launch(void* const* d_in, const int* in_sizes, int n_in,
                              void* d_out, int out_size, void* d_ws, size_t ws_size,
                              hipStream_t stream) {
    const float* x     = (const float*)d_in[0];
    const float* w_qkv = (const float*)d_in[1];
    const float* w_out = (const float*)d_in[2];
    float* out = (float*)d_out;

    char* ws = (char*)d_ws;
    unsigned short* qT  = (unsigned short*)ws;                    // 67,108,864 B
    unsigned short* wt  = (unsigned short*)(ws + 67108864);       //    786,432 B
    float* lsum = (float*)(ws + 67895296);                        //     32,768 B
    float* phi  = (float*)(ws + 67928064);                        //  2,097,152 B
    unsigned short* Mbf = (unsigned short*)(ws + 70025216);       //  4,194,304 B
    unsigned short* xT  = (unsigned short*)(ws + 74219520);       // 33,554,432 B
    // total ws: 107,773,952 B (~103 MiB)

    hipMemsetAsync(lsum, 0, (8192 + 524288) * sizeof(float), stream);

    cvt_w<<<192, 256, 0, stream>>>(w_qkv, wt);
    cvt_xT<<<dim3(64, 4, 16), 256, 0, stream>>>(x, xT);
    qkv_phi<<<dim3(8, 8, 16), 256, 0, stream>>>(xT, wt, qT, phi, lsum);
    build_M<<<dim3(8, 16), 256, 0, stream>>>(phi, lsum, w_out, Mbf);
    out_mfma<<<dim3(32, 2, 16), 256, 0, stream>>>(Mbf, qT, out);
}

// Round 6
// 328.467 us; speedup vs baseline: 1.4096x; 1.4096x over previous
//
#include <hip/hip_runtime.h>
#include <hip/hip_bf16.h>

// LinearAttention MI355X: B=16, C=256, n=4096, h=8, d=64, SCALE=0.125
// R5: every MFMA operand load is lane-contiguous.
//   K0 cvt_w_frag: w_qkv -> wf fragment-major [op][h][w][ks][lane][8]
//   K1 cvt_xT    : xT[b][n][c] = bf16(x[b][c][n])
//   K2 qkv_phi   : per (b,h,512n): Bs LDS dbuf from xT, A-frags coalesced
//                  from wf; q-softmax -> qf (fragment-major); exp(k)/v ->
//                  swizzled LDS -> phi MFMA; lsum/phi atomics
//   K3 build_M   : Mf (fragment-major) = bf16(w_out · phi / lsum)
//   K4 out_mfma  : out = M · q, LDS-free, all-coalesced fragment loads
// ws: qf 64MB | wf 0.75MB | lsum | phi 2MB | Mf 4MB | xT 32MB (same as R4)

typedef __attribute__((ext_vector_type(8))) short bf16x8;
typedef __attribute__((ext_vector_type(4))) float f32x4;

__device__ __forceinline__ unsigned short f2bf(float f) {
    union { float f; unsigned int i; } w; w.f = f;
    unsigned int r = w.i + 0x7FFFu + ((w.i >> 16) & 1u);
    return (unsigned short)(r >> 16);
}

// ---------------- K0: w_qkv -> fragment-major bf16 ----------------
// granule g: lane=g&63, ks=(g>>6)&7, w2=(g>>9)&3, h=(g>>11)&7, op=g>>14
__global__ __launch_bounds__(256) void cvt_w_frag(
    const float* __restrict__ wqkv, unsigned short* __restrict__ wf)
{
    int g = blockIdx.x * 256 + threadIdx.x;    // 49152 granules, grid 192
    int lane = g & 63;
    int ks   = (g >> 6) & 7;
    int w2   = (g >> 9) & 3;
    int h    = (g >> 11) & 7;
    int op   = g >> 14;
    int row = op * 512 + h * 64 + w2 * 16 + (lane & 15);
    int col = ks * 32 + (lane >> 4) * 8;
    const float* src = &wqkv[(size_t)row * 256 + col];
    float4 f0 = *(const float4*)&src[0];
    float4 f1 = *(const float4*)&src[4];
    unsigned short t[8] = {f2bf(f0.x), f2bf(f0.y), f2bf(f0.z), f2bf(f0.w),
                           f2bf(f1.x), f2bf(f1.y), f2bf(f1.z), f2bf(f1.w)};
    *(uint4*)&wf[(size_t)g * 8] = *(uint4*)t;
}

// ---------------- K1: x[b][c][n] f32 -> xT[b][n][c] bf16 ----------------
__global__ __launch_bounds__(256) void cvt_xT(
    const float* __restrict__ x, unsigned short* __restrict__ xT)
{
    const int nb = blockIdx.x * 64, cb = blockIdx.y * 64, b = blockIdx.z;
    __shared__ float Ts[64 * 65];
    const int tid = threadIdx.x;
    const int l = tid & 63, w = tid >> 6;
    const float* xb = x + ((size_t)b * 256 + cb) * 4096 + nb;
#pragma unroll
    for (int p = 0; p < 4; p++) {
        int c = p * 16 + (tid >> 4);
        int n4 = (tid & 15) * 4;
        float4 v = *(const float4*)&xb[(size_t)c * 4096 + n4];
        Ts[c * 65 + n4 + 0] = v.x; Ts[c * 65 + n4 + 1] = v.y;
        Ts[c * 65 + n4 + 2] = v.z; Ts[c * 65 + n4 + 3] = v.w;
    }
    __syncthreads();
    unsigned short t[16];
#pragma unroll
    for (int i = 0; i < 16; i++) t[i] = f2bf(Ts[(w * 16 + i) * 65 + l]);
    unsigned short* dst = xT + ((size_t)b * 4096 + nb + l) * 256 + cb + w * 16;
    *(uint4*)&dst[0] = *(uint4*)&t[0];
    *(uint4*)&dst[8] = *(uint4*)&t[8];
}

// ---------------- K2: fused q/k/v GEMM + softmax(q) + phi ----------------
// grid (8 ch, 8 h, 16 b), block 256 (4 waves)
// LDS 53,248 B -> 3 blocks/CU. Es[64][128] | Vs[64][128] | union(Qs[128][72],
// Bs[2][128][40]) ; red (640 f32) aliases Es rows 0..9 (dead by then).
__global__ __launch_bounds__(256) void qkv_phi(
    const unsigned short* __restrict__ xT, const unsigned short* __restrict__ wf,
    unsigned short* __restrict__ qf, float* __restrict__ phi,
    float* __restrict__ lsum)
{
    const int ch = blockIdx.x;
    const int h  = blockIdx.y;
    const int b  = blockIdx.z;
    const int tid  = threadIdx.x;
    const int lane = tid & 63;
    const int w    = tid >> 6;
    const int quad = lane >> 4;
    const int l15  = lane & 15;

    __shared__ unsigned short smem[26624];     // 53,248 B
    unsigned short* Es = smem;                 // [64][128]
    unsigned short* Vs = smem + 8192;          // [64][128]
    unsigned short* Qs = smem + 16384;         // [128][72] (union w/ Bs)
    unsigned short* Bs = smem + 16384;         // [2][128][40]
    float* red = (float*)smem;                 // 640 f32, aliases Es[0..9]

    // fragment-major weight bases (coalesced: lane*8 shorts)
    const unsigned short* wfq = wf + ((size_t)((0 * 8 + h) * 4 + w) * 8) * 512 + lane * 8;
    const unsigned short* wfk = wf + ((size_t)((1 * 8 + h) * 4 + w) * 8) * 512 + lane * 8;
    const unsigned short* wfv = wf + ((size_t)((2 * 8 + h) * 4 + w) * 8) * 512 + lane * 8;

    f32x4 pacc[4];
#pragma unroll
    for (int i = 0; i < 4; i++) pacc[i] = (f32x4)(0.f);
    float lacc[4] = {0.f, 0.f, 0.f, 0.f};

    const int srow = tid >> 1;                 // staging row 0..127
    const int sch  = (tid & 1) * 16;           // 0/16 shorts (32 B per thread)

    for (int st = 0; st < 4; st++) {
        const int nb = ch * 512 + st * 128;
        const unsigned short* xrow =
            xT + ((size_t)b * 4096 + nb + srow) * 256 + sch;

        f32x4 accq[8], acck[8], accv[8];
#pragma unroll
        for (int i = 0; i < 8; i++) {
            accq[i] = (f32x4)(0.f); acck[i] = (f32x4)(0.f); accv[i] = (f32x4)(0.f);
        }

        // prologue: stage ks=0 into buf 0
        {
            uint4 p0 = *(const uint4*)&xrow[0];
            uint4 p1 = *(const uint4*)&xrow[8];
            unsigned short* bw = Bs + srow * 40 + sch;
            *(uint4*)&bw[0] = p0;
            *(uint4*)&bw[8] = p1;
        }
        __syncthreads();

        for (int ks = 0; ks < 8; ks++) {
            const int buf = ks & 1;
            uint4 n0, n1;
            if (ks < 7) {
                n0 = *(const uint4*)&xrow[(ks + 1) * 32];
                n1 = *(const uint4*)&xrow[(ks + 1) * 32 + 8];
            }
            bf16x8 aq = *(const bf16x8*)&wfq[ks * 512];
            bf16x8 ak = *(const bf16x8*)&wfk[ks * 512];
            bf16x8 av = *(const bf16x8*)&wfv[ks * 512];
            const unsigned short* bsr = Bs + buf * 5120 + l15 * 40 + quad * 8;
#pragma unroll
            for (int nt = 0; nt < 8; nt++) {
                bf16x8 bv = *(const bf16x8*)&bsr[nt * 640];   // 16 rows * 40
                accq[nt] = __builtin_amdgcn_mfma_f32_16x16x32_bf16(aq, bv, accq[nt], 0, 0, 0);
                acck[nt] = __builtin_amdgcn_mfma_f32_16x16x32_bf16(ak, bv, acck[nt], 0, 0, 0);
                accv[nt] = __builtin_amdgcn_mfma_f32_16x16x32_bf16(av, bv, accv[nt], 0, 0, 0);
            }
            if (ks < 7) {
                unsigned short* bw = Bs + (buf ^ 1) * 5120 + srow * 40 + sch;
                *(uint4*)&bw[0] = n0;
                *(uint4*)&bw[8] = n1;
                __syncthreads();
            }
        }

        // ---- q epilogue: softmax over d (64 rows), -> qf fragment-major ----
#pragma unroll
        for (int nt = 0; nt < 8; nt++) {
#pragma unroll
            for (int r = 0; r < 4; r++) accq[nt][r] = __expf(accq[nt][r]);
            float s = accq[nt][0] + accq[nt][1] + accq[nt][2] + accq[nt][3];
            s += __shfl_xor(s, 16);
            s += __shfl_xor(s, 32);
            if (quad == 0) red[w * 128 + nt * 16 + l15] = s;
        }
        __syncthreads();                       // S2
        if (tid < 128) {
            float t = red[tid] + red[128 + tid] + red[256 + tid] + red[384 + tid];
            red[512 + tid] = 0.125f / t;
        }
        __syncthreads();                       // S3
#pragma unroll
        for (int nt = 0; nt < 8; nt++) {
            float li = red[512 + nt * 16 + l15];
            uint2 pp;
            pp.x = (unsigned int)f2bf(accq[nt][0] * li) |
                   ((unsigned int)f2bf(accq[nt][1] * li) << 16);
            pp.y = (unsigned int)f2bf(accq[nt][2] * li) |
                   ((unsigned int)f2bf(accq[nt][3] * li) << 16);
            *(uint2*)&Qs[(nt * 16 + l15) * 72 + w * 16 + quad * 4] = pp;
        }
        __syncthreads();                       // S4
        {
            // qf granule: ((((b*32+nbIdx)*16 + ks)*8 + nt)*64 + quad*16 + l15)
            const int n = tid >> 1, half = tid & 1;
            const int nbIdx = ch * 4 + st;
            const int ksq = h * 2 + half;
            const size_t gbase =
                (((size_t)(b * 32 + nbIdx) * 16 + ksq) * 8 + (n >> 4)) * 64 + (n & 15);
#pragma unroll
            for (int u = 0; u < 4; u++)
                *(uint4*)&qf[(gbase + u * 16) * 8] = *(uint4*)&Qs[n * 72 + half * 32 + u * 8];
        }

        // ---- k/v epilogue: exp, lsum partials, swizzled deposit ----
#pragma unroll
        for (int r = 0; r < 4; r++) {
            const int dl = quad * 4 + r;                            // d & 15
            const int dbase = (w * 16 + dl) * 256 + (l15 & 7) * 2;  // byte off
#pragma unroll
            for (int nt = 0; nt < 8; nt++) {
                const int pos = (2 * nt + (l15 >> 3)) ^ dl;
                float ek = __expf(acck[nt][r]);
                lacc[r] += ek;
                *(unsigned short*)((char*)Es + dbase + pos * 16) = f2bf(ek);
                *(unsigned short*)((char*)Vs + dbase + pos * 16) = f2bf(accv[nt][r]);
            }
        }
        __syncthreads();                       // S6

        // phi MFMA: phi[d][e] += sum_n expk[d][n] v[e][n], K=128
#pragma unroll
        for (int k2 = 0; k2 < 4; k2++) {
            bf16x8 ae = *(bf16x8*)((char*)Es + (w * 16 + l15) * 256 +
                                   (((k2 * 4 + quad) ^ l15) * 16));
#pragma unroll
            for (int et = 0; et < 4; et++) {
                bf16x8 bv = *(bf16x8*)((char*)Vs + (et * 16 + l15) * 256 +
                                       (((k2 * 4 + quad) ^ l15) * 16));
                pacc[et] = __builtin_amdgcn_mfma_f32_16x16x32_bf16(ae, bv, pacc[et], 0, 0, 0);
            }
        }
        // next st: prologue writes Bs (union w/ Qs) — safe: all Qs reads
        // finished before S6; Es/Vs reads fenced by next S2.
    }

    // lsum: reduce over l15 then one atomic per d-row
#pragma unroll
    for (int r = 0; r < 4; r++) {
        float s = lacc[r];
        s += __shfl_xor(s, 1); s += __shfl_xor(s, 2);
        s += __shfl_xor(s, 4); s += __shfl_xor(s, 8);
        if (l15 == 0)
            atomicAdd(&lsum[((size_t)b * 8 + h) * 64 + w * 16 + quad * 4 + r], s);
    }
    float* pp = phi + ((size_t)b * 8 + h) * 4096;
#pragma unroll
    for (int et = 0; et < 4; et++)
#pragma unroll
        for (int r = 0; r < 4; r++)
            atomicAdd(&pp[(w * 16 + quad * 4 + r) * 64 + et * 16 + l15], pacc[et][r]);
}

// ---------------- K3: Mf = w_out · (phi/l), fragment-major bf16 ----------------
// grid (8 h, 16 b), block 256 (thread = c)
__global__ __launch_bounds__(256) void build_M(
    const float* __restrict__ phi, const float* __restrict__ lsum,
    const float* __restrict__ w_out, unsigned short* __restrict__ Mf)
{
    const int h = blockIdx.x, b = blockIdx.y;
    __shared__ float pT[64][68];  // [e][d]
    const float* pp = phi + ((size_t)b * 8 + h) * 4096;  // [d][e]
    const int tid = threadIdx.x;
    const int row = tid >> 2, ls = tid & 3;
#pragma unroll
    for (int u = 0; u < 4; u++) {
        int e0 = (ls + u * 4) * 4;
        float4 v = *(const float4*)&pp[row * 64 + e0];
        pT[e0 + 0][row] = v.x; pT[e0 + 1][row] = v.y;
        pT[e0 + 2][row] = v.z; pT[e0 + 3][row] = v.w;
    }
    __syncthreads();
    const int c = tid;
    float acc[64];
#pragma unroll
    for (int d = 0; d < 64; d++) acc[d] = 0.f;
    for (int e4 = 0; e4 < 16; e4++) {
        float4 wv = *(const float4*)&w_out[(size_t)c * 512 + h * 64 + e4 * 4];
        float wq[4] = {wv.x, wv.y, wv.z, wv.w};
#pragma unroll
        for (int qq = 0; qq < 4; qq++) {
            int e = e4 * 4 + qq;
#pragma unroll
            for (int d4 = 0; d4 < 16; d4++) {
                float4 p = *(const float4*)&pT[e][d4 * 4];
                acc[d4 * 4 + 0] += wq[qq] * p.x;
                acc[d4 * 4 + 1] += wq[qq] * p.y;
                acc[d4 * 4 + 2] += wq[qq] * p.z;
                acc[d4 * 4 + 3] += wq[qq] * p.w;
            }
        }
    }
    const float* lrow = lsum + ((size_t)b * 8 + h) * 64;
    unsigned short tmp[64];
#pragma unroll
    for (int d = 0; d < 64; d++) tmp[d] = f2bf(acc[d] / lrow[d]);
    // Mf granule: ((((b*2+ct)*2+wr)*4+mi)*16 + ks)*64 + quad*16 + l15c
    const int ct = c >> 7, wr = (c >> 6) & 1, mi = (c >> 4) & 3, l15c = c & 15;
#pragma unroll
    for (int u = 0; u < 8; u++) {
        const int ksA = h * 2 + (u >> 2);
        const int quadA = u & 3;
        size_t gidx = ((((size_t)(b * 2 + ct) * 2 + wr) * 4 + mi) * 16 + ksA) * 64
                      + quadA * 16 + l15c;
        *(uint4*)&Mf[gidx * 8] = *(uint4*)&tmp[u * 8];
    }
}

// ---------------- K4: out = M · q, LDS-free, all-coalesced ----------------
// grid (32 nblocks, 2 ctiles, 16 b), block 256 (4 waves, 2x2)
__global__ __launch_bounds__(256) void out_mfma(
    const unsigned short* __restrict__ Mf, const unsigned short* __restrict__ qf,
    float* __restrict__ out)
{
    const int nbIdx = blockIdx.x;
    const int ct    = blockIdx.y;
    const int b     = blockIdx.z;
    const int tid  = threadIdx.x;
    const int lane = tid & 63;
    const int w    = tid >> 6;
    const int wr   = w >> 1, wc = w & 1;
    const int quad = lane >> 4;
    const int l15  = lane & 15;

    f32x4 acc[4][4];
#pragma unroll
    for (int i = 0; i < 4; i++)
#pragma unroll
        for (int j = 0; j < 4; j++) acc[i][j] = (f32x4)(0.f);

    const unsigned short* Ab =
        Mf + ((((size_t)(b * 2 + ct) * 2 + wr) * 4) * 16) * 512 + lane * 8;
    const unsigned short* Bb =
        qf + (((size_t)(b * 32 + nbIdx) * 16) * 8) * 512 + lane * 8;

    for (int ks = 0; ks < 16; ks++) {
        bf16x8 af[4], bv[4];
#pragma unroll
        for (int mi = 0; mi < 4; mi++)
            af[mi] = *(const bf16x8*)&Ab[(size_t)(mi * 16 + ks) * 512];
#pragma unroll
        for (int ni = 0; ni < 4; ni++)
            bv[ni] = *(const bf16x8*)&Bb[(size_t)(ks * 8 + wc * 4 + ni) * 512];
#pragma unroll
        for (int mi = 0; mi < 4; mi++)
#pragma unroll
            for (int ni = 0; ni < 4; ni++)
                acc[mi][ni] = __builtin_amdgcn_mfma_f32_16x16x32_bf16(
                    af[mi], bv[ni], acc[mi][ni], 0, 0, 0);
    }
    float* ob = out + ((size_t)b * 256 + ct * 128 + wr * 64) * 4096
                + nbIdx * 128 + wc * 64;
#pragma unroll
    for (int mi = 0; mi < 4; mi++)
#pragma unroll
        for (int ni = 0; ni < 4; ni++)
#pragma unroll
            for (int r = 0; r < 4; r++)
                ob[(size_t)(mi * 16 + quad * 4 + r) * 4096 + ni * 16 + l15]
                    = acc[mi][ni][r];
}

extern "C" void kernel_launch(void* const* d_in, const int* in_sizes, int n_in,
                              void* d_out, int out_size, void* d_ws, size_t ws_size,
                              hipStream_t stream) {
    const float* x     = (const float*)d_in[0];
    const float* w_qkv = (const float*)d_in[1];
    const float* w_out = (const float*)d_in[2];
    float* out = (float*)d_out;

    char* ws = (char*)d_ws;
    unsigned short* qf = (unsigned short*)ws;                     // 67,108,864 B
    unsigned short* wf = (unsigned short*)(ws + 67108864);        //    786,432 B
    float* lsum = (float*)(ws + 67895296);                        //     32,768 B
    float* phi  = (float*)(ws + 67928064);                        //  2,097,152 B
    unsigned short* Mf = (unsigned short*)(ws + 70025216);        //  4,194,304 B
    unsigned short* xT = (unsigned short*)(ws + 74219520);        // 33,554,432 B
    // total ws: 107,773,952 B (same as R4, proven safe)

    hipMemsetAsync(lsum, 0, (8192 + 524288) * sizeof(float), stream);

    cvt_w_frag<<<192, 256, 0, stream>>>(w_qkv, wf);
    cvt_xT<<<dim3(64, 4, 16), 256, 0, stream>>>(x, xT);
    qkv_phi<<<dim3(8, 8, 16), 256, 0, stream>>>(xT, wf, qf, phi, lsum);
    build_M<<<dim3(8, 16), 256, 0, stream>>>(phi, lsum, w_out, Mf);
    out_mfma<<<dim3(32, 2, 16), 256, 0, stream>>>(Mf, qf, out);
}